// Round 3
// baseline (232.781 us; speedup 1.0000x reference)
//
#include <hip/hip_runtime.h>

#define VOCAB 50000
#define BROWS 4096
#define F 64
#define NCOLS 80            // 64 features + w_hi + w_lo + 14 zero pad
#define NT 5                // n-tiles of 16
#define SPLITS 16
#define KT_PER_SPLIT 98     // K-tiles (of 32) per split
#define NR 49               // rounds per split (2 K-tiles per round)
#define KT_TOTAL (SPLITS * KT_PER_SPLIT)  // 1568
#define KPAD (KT_TOTAL * 32)              // 50176

#define AS1 __attribute__((address_space(1)))
#define AS3 __attribute__((address_space(3)))

typedef __attribute__((ext_vector_type(4))) float f32x4;
typedef __attribute__((ext_vector_type(8))) short s16x8;

__device__ __forceinline__ unsigned short f2bf(float f) {
    unsigned u = __builtin_bit_cast(unsigned, f);
    unsigned r = (u + 0x7FFFu + ((u >> 16) & 1u)) >> 16;   // round-to-nearest-even
    return (unsigned short)r;
}
__device__ __forceinline__ float bf2f(unsigned short b) {
    unsigned u = ((unsigned)b) << 16;
    return __builtin_bit_cast(float, u);
}

// --- kernel 1: w[k] = bias[k] - 0.5*||V[k]||^2 (0 for padded k) ---
__global__ void fm_prep_w(const float* __restrict__ V, const float* __restrict__ bias,
                          float* __restrict__ w) {
    int k = blockIdx.x * blockDim.x + threadIdx.x;
    if (k >= KPAD) return;
    float val = 0.f;
    if (k < VOCAB) {
        const float4* row = reinterpret_cast<const float4*>(V + (size_t)k * F);
        float ss = 0.f;
#pragma unroll
        for (int j = 0; j < F / 4; ++j) {
            float4 v = row[j];
            ss += v.x * v.x + v.y * v.y + v.z * v.z + v.w * v.w;
        }
        val = bias[k] - 0.5f * ss;
    }
    w[k] = val;
}

// --- kernel 2: pack B operand into MFMA 16x16x32 bf16 fragment order ---
// bfrag[(kt*NT + nt)*64 + lane] = uint4 of 8 bf16:
//   elem j = B[kt*32 + (lane>>4)*8 + j][nt*16 + (lane&15)]
// where B[k][n] = V[k][n] (n<64), w_hi[k] (n==64), w_lo[k] (n==65), 0 otherwise.
__global__ void fm_prep_bfrag(const float* __restrict__ V, const float* __restrict__ w,
                              uint4* __restrict__ bfrag) {
    int t = blockIdx.x * blockDim.x + threadIdx.x;
    if (t >= KT_TOTAL * NT * 64) return;
    int lane = t & 63;
    int tile = t >> 6;
    int nt = tile % NT;
    int kt = tile / NT;
    int n = nt * 16 + (lane & 15);
    int kbase = kt * 32 + (lane >> 4) * 8;
    unsigned short o[8];
#pragma unroll
    for (int j = 0; j < 8; ++j) {
        int k = kbase + j;
        float v = 0.f;
        if (k < VOCAB) {
            if (n < F) {
                v = V[(size_t)k * F + n];
            } else if (n == F) {
                v = w[k];                       // f2bf below -> w_hi
            } else if (n == F + 1) {
                float wv = w[k];
                v = wv - bf2f(f2bf(wv));        // residual -> w_lo
            }
        }
        o[j] = f2bf(v);
    }
    uint4 pk;
    pk.x = (unsigned)o[0] | ((unsigned)o[1] << 16);
    pk.y = (unsigned)o[2] | ((unsigned)o[3] << 16);
    pk.z = (unsigned)o[4] | ((unsigned)o[5] << 16);
    pk.w = (unsigned)o[6] | ((unsigned)o[7] << 16);
    bfrag[t] = pk;
}

// --- kernel 3: split-K MFMA GEMM, 2 K-tiles/round, x reg-prefetch, LDS dbuf B ---
__global__ __launch_bounds__(256, 4) void fm_main(const int* __restrict__ x,
                                                  const uint4* __restrict__ bfrag,
                                                  float* __restrict__ part) {
    __shared__ uint4 bbuf[2][2 * NT * 64];    // 2 x 10240 B
    const int bx = blockIdx.x;
    const int split = bx & (SPLITS - 1);
    const int mblock = bx >> 4;
    const int tid = threadIdx.x;
    const int wave = tid >> 6;
    const int lane = tid & 63;
    const int kb = lane >> 4;                 // 0..3
    const int rowA = mblock * 64 + wave * 16 + (lane & 15);
    const int* __restrict__ xrow = x + (size_t)rowA * VOCAB;
    const int kt0 = split * KT_PER_SPLIT;
    const int e0 = (wave << 6) + lane;

    auto stage = [&](int buf, int rnd) {      // 640 uint4 = 2 B-tiles -> LDS
        const uint4* src = bfrag + (size_t)(kt0 + 2 * rnd) * (NT * 64);
        __builtin_amdgcn_global_load_lds((const AS1 void*)(src + e0),
                                         (AS3 void*)(&bbuf[buf][wave << 6]), 16, 0, 0);
        __builtin_amdgcn_global_load_lds((const AS1 void*)(src + 256 + e0),
                                         (AS3 void*)(&bbuf[buf][256 + (wave << 6)]), 16, 0, 0);
        if (wave < 2)
            __builtin_amdgcn_global_load_lds((const AS1 void*)(src + 512 + e0),
                                             (AS3 void*)(&bbuf[buf][512 + (wave << 6)]), 16, 0, 0);
    };
    auto loadx = [&](int rnd, int4* dst) {    // unguarded: 64 K-elems for this lane's kb
        const int k = (kt0 + 2 * rnd) * 32 + kb * 8;
        dst[0] = *reinterpret_cast<const int4*>(xrow + k);
        dst[1] = *reinterpret_cast<const int4*>(xrow + k + 4);
        dst[2] = *reinterpret_cast<const int4*>(xrow + k + 32);
        dst[3] = *reinterpret_cast<const int4*>(xrow + k + 36);
    };
    auto loadx_g = [&](int rnd, int4* dst) {  // guarded tail (split 15, rounds 46..48)
        const int k = (kt0 + 2 * rnd) * 32 + kb * 8;
        int v[16];
#pragma unroll
        for (int j = 0; j < 8; ++j) v[j] = (k + j < VOCAB) ? xrow[k + j] : 0;
#pragma unroll
        for (int j = 0; j < 8; ++j) v[8 + j] = (k + 32 + j < VOCAB) ? xrow[k + 32 + j] : 0;
        dst[0] = make_int4(v[0], v[1], v[2], v[3]);
        dst[1] = make_int4(v[4], v[5], v[6], v[7]);
        dst[2] = make_int4(v[8], v[9], v[10], v[11]);
        dst[3] = make_int4(v[12], v[13], v[14], v[15]);
    };
    auto mk = [&](int4 a0, int4 a1) -> s16x8 { // x in {0,1}: bf16(1.0) = 0x3F80
        uint4 apk;
        apk.x = ((unsigned)a0.x + ((unsigned)a0.y << 16)) * 16256u;
        apk.y = ((unsigned)a0.z + ((unsigned)a0.w << 16)) * 16256u;
        apk.z = ((unsigned)a1.x + ((unsigned)a1.y << 16)) * 16256u;
        apk.w = ((unsigned)a1.z + ((unsigned)a1.w << 16)) * 16256u;
        return __builtin_bit_cast(s16x8, apk);
    };

    f32x4 acc[NT];
#pragma unroll
    for (int nt = 0; nt < NT; ++nt) acc[nt] = (f32x4){0.f, 0.f, 0.f, 0.f};

    int4 xr[4], nx[4];
    stage(0, 0);
    loadx(0, xr);
    __syncthreads();

    const int nfast = (split == SPLITS - 1) ? 46 : NR;  // rounds with unguarded x-load
    int buf = 0;
    for (int r = 0; r < NR; ++r) {
        if (r + 1 < NR) {
            stage(buf ^ 1, r + 1);            // B for next round -> other LDS buffer
            if (r + 1 < nfast) loadx(r + 1, nx);
            else               loadx_g(r + 1, nx);
        }
        s16x8 af0 = mk(xr[0], xr[1]);
        s16x8 af1 = mk(xr[2], xr[3]);
#pragma unroll
        for (int nt = 0; nt < NT; ++nt) {
            s16x8 b0 = __builtin_bit_cast(s16x8, bbuf[buf][nt * 64 + lane]);
            acc[nt] = __builtin_amdgcn_mfma_f32_16x16x32_bf16(af0, b0, acc[nt], 0, 0, 0);
        }
#pragma unroll
        for (int nt = 0; nt < NT; ++nt) {
            s16x8 b1 = __builtin_bit_cast(s16x8, bbuf[buf][320 + nt * 64 + lane]);
            acc[nt] = __builtin_amdgcn_mfma_f32_16x16x32_bf16(af1, b1, acc[nt], 0, 0, 0);
        }
        __syncthreads();
        xr[0] = nx[0]; xr[1] = nx[1]; xr[2] = nx[2]; xr[3] = nx[3];
        buf ^= 1;
    }

    // D layout: row = (lane>>4)*4 + r, col = lane&15 (within the 16x16 tile)
    float* __restrict__ p = part + (size_t)split * BROWS * NCOLS;
    int m0 = mblock * 64 + wave * 16 + kb * 4;
    int c0 = lane & 15;
#pragma unroll
    for (int nt = 0; nt < NT; ++nt)
#pragma unroll
        for (int r = 0; r < 4; ++r)
            p[(size_t)(m0 + r) * NCOLS + nt * 16 + c0] = acc[nt][r];
}

// --- kernel 4: reduce splits, square-sum, add linear term ---
__global__ void fm_reduce(const float* __restrict__ part, const float* __restrict__ gbias,
                          float* __restrict__ out) {
    int b = blockIdx.x * 4 + (threadIdx.x >> 6);
    int lane = threadIdx.x & 63;
    float acc = 0.f;
#pragma unroll
    for (int s = 0; s < SPLITS; ++s)
        acc += part[((size_t)s * BROWS + b) * NCOLS + lane];
    float sq = acc * acc;
    float ex = 0.f;
    if (lane < 16)       ex = part[((size_t)lane * BROWS + b) * NCOLS + F];
    else if (lane < 32)  ex = part[((size_t)(lane - 16) * BROWS + b) * NCOLS + F + 1];
#pragma unroll
    for (int off = 32; off; off >>= 1) {
        sq += __shfl_xor(sq, off, 64);
        ex += __shfl_xor(ex, off, 64);
    }
    if (lane == 0) out[b] = gbias[0] + ex + 0.5f * sq;
}

extern "C" void kernel_launch(void* const* d_in, const int* in_sizes, int n_in,
                              void* d_out, int out_size, void* d_ws, size_t ws_size,
                              hipStream_t stream) {
    const int*   x     = (const int*)d_in[0];
    const float* V     = (const float*)d_in[1];
    const float* bias  = (const float*)d_in[2];
    const float* gbias = (const float*)d_in[3];
    float* out = (float*)d_out;

    // workspace layout
    char* ws = (char*)d_ws;
    uint4* bfrag = (uint4*)ws;                                  // 8,028,160 B
    float* w     = (float*)(ws + (size_t)KT_TOTAL * NT * 64 * 16);
    float* part  = (float*)(ws + (size_t)KT_TOTAL * NT * 64 * 16 + (size_t)KPAD * 4);
    // total: 8,028,160 + 200,704 + 20,971,520 = 29,200,384 B

    fm_prep_w<<<(KPAD + 255) / 256, 256, 0, stream>>>(V, bias, w);
    fm_prep_bfrag<<<(KT_TOTAL * NT * 64 + 255) / 256, 256, 0, stream>>>(V, w, bfrag);
    fm_main<<<(BROWS / 64) * SPLITS, 256, 0, stream>>>(x, bfrag, part);
    fm_reduce<<<BROWS / 4, 256, 0, stream>>>(part, gbias, out);
}

// Round 4
// 209.065 us; speedup vs baseline: 1.1134x; 1.1134x over previous
//
#include <hip/hip_runtime.h>

#define VOCAB 50000
#define BROWS 4096
#define F 64
#define NCOLS 80            // 64 features + w_hi + w_lo + 14 zero pad
#define NT 5                // n-tiles of 16
#define SPLITS 16
#define NR 98               // K-tiles (of 32) per split
#define KT_TOTAL (SPLITS * NR)            // 1568
#define KPAD (KT_TOTAL * 32)              // 50176

#define AS1 __attribute__((address_space(1)))
#define AS3 __attribute__((address_space(3)))

typedef __attribute__((ext_vector_type(4))) float f32x4;
typedef __attribute__((ext_vector_type(8))) short s16x8;

__device__ __forceinline__ unsigned short f2bf(float f) {
    unsigned u = __builtin_bit_cast(unsigned, f);
    unsigned r = (u + 0x7FFFu + ((u >> 16) & 1u)) >> 16;   // round-to-nearest-even
    return (unsigned short)r;
}
__device__ __forceinline__ float bf2f(unsigned short b) {
    unsigned u = ((unsigned)b) << 16;
    return __builtin_bit_cast(float, u);
}

// --- kernel 1: w[k] = bias[k] - 0.5*||V[k]||^2 (0 for padded k) ---
__global__ void fm_prep_w(const float* __restrict__ V, const float* __restrict__ bias,
                          float* __restrict__ w) {
    int k = blockIdx.x * blockDim.x + threadIdx.x;
    if (k >= KPAD) return;
    float val = 0.f;
    if (k < VOCAB) {
        const float4* row = reinterpret_cast<const float4*>(V + (size_t)k * F);
        float ss = 0.f;
#pragma unroll
        for (int j = 0; j < F / 4; ++j) {
            float4 v = row[j];
            ss += v.x * v.x + v.y * v.y + v.z * v.z + v.w * v.w;
        }
        val = bias[k] - 0.5f * ss;
    }
    w[k] = val;
}

// --- kernel 2: pack B operand into MFMA 16x16x32 bf16 fragment order ---
// bfrag[(kt*NT + nt)*64 + lane] = uint4 of 8 bf16:
//   elem j = B[kt*32 + (lane>>4)*8 + j][nt*16 + (lane&15)]
// where B[k][n] = V[k][n] (n<64), w_hi[k] (n==64), w_lo[k] (n==65), 0 otherwise.
__global__ void fm_prep_bfrag(const float* __restrict__ V, const float* __restrict__ w,
                              uint4* __restrict__ bfrag) {
    int t = blockIdx.x * blockDim.x + threadIdx.x;
    if (t >= KT_TOTAL * NT * 64) return;
    int lane = t & 63;
    int tile = t >> 6;
    int nt = tile % NT;
    int kt = tile / NT;
    int n = nt * 16 + (lane & 15);
    int kbase = kt * 32 + (lane >> 4) * 8;
    unsigned short o[8];
#pragma unroll
    for (int j = 0; j < 8; ++j) {
        int k = kbase + j;
        float v = 0.f;
        if (k < VOCAB) {
            if (n < F) {
                v = V[(size_t)k * F + n];
            } else if (n == F) {
                v = w[k];                       // f2bf below -> w_hi
            } else if (n == F + 1) {
                float wv = w[k];
                v = wv - bf2f(f2bf(wv));        // residual -> w_lo
            }
        }
        o[j] = f2bf(v);
    }
    uint4 pk;
    pk.x = (unsigned)o[0] | ((unsigned)o[1] << 16);
    pk.y = (unsigned)o[2] | ((unsigned)o[3] << 16);
    pk.z = (unsigned)o[4] | ((unsigned)o[5] << 16);
    pk.w = (unsigned)o[6] | ((unsigned)o[7] << 16);
    bfrag[t] = pk;
}

// --- kernel 3: split-K MFMA GEMM; counted-vmcnt rounds, x reg-prefetch, LDS dbuf B ---
__global__ __launch_bounds__(256, 4) void fm_main(const int* __restrict__ x,
                                                  const uint4* __restrict__ bfrag,
                                                  float* __restrict__ part) {
    __shared__ uint4 bbuf[2][NT * 64];        // 2 x 5120 B
    const int bid = blockIdx.x;
    // XCD-locality remap: XCD k (bid&7) sees only splits {2k, 2k+1} ->
    // bfrag working set per XCD-L2 = 2 x 500KB (fits 4MB), vs 8MB with bid&15.
    const int split = (bid & 7) * 2 + ((bid >> 3) & 1);
    const int mblock = bid >> 4;
    const int tid = threadIdx.x;
    const int wave = tid >> 6;
    const int lane = tid & 63;
    const int kb = lane >> 4;                 // 0..3
    const int rowA = mblock * 64 + wave * 16 + (lane & 15);
    const int* __restrict__ xrow = x + (size_t)rowA * VOCAB;
    const int kt0 = split * NR;
    const int e0 = (wave << 6) + lane;

    auto stage = [&](int rnd) {               // 320 uint4 (one B-tile) -> bbuf[rnd&1]
        const uint4* src = bfrag + (size_t)(kt0 + rnd) * (NT * 64);
        uint4* dst = bbuf[rnd & 1];
        __builtin_amdgcn_global_load_lds((const AS1 void*)(src + e0),
                                         (AS3 void*)(dst + (wave << 6)), 16, 0, 0);
        if (wave == 0)                        // elems 256..319
            __builtin_amdgcn_global_load_lds((const AS1 void*)(src + 256 + lane),
                                             (AS3 void*)(dst + 256), 16, 0, 0);
    };
    auto mk = [&](int4 a0, int4 a1) -> s16x8 { // x in {0,1}: bf16(1.0) = 0x3F80
        uint4 apk;
        apk.x = ((unsigned)a0.x + ((unsigned)a0.y << 16)) * 16256u;
        apk.y = ((unsigned)a0.z + ((unsigned)a0.w << 16)) * 16256u;
        apk.z = ((unsigned)a1.x + ((unsigned)a1.y << 16)) * 16256u;
        apk.w = ((unsigned)a1.z + ((unsigned)a1.w << 16)) * 16256u;
        return __builtin_bit_cast(s16x8, apk);
    };

    f32x4 acc[NT];
#pragma unroll
    for (int nt = 0; nt < NT; ++nt) acc[nt] = (f32x4){0.f, 0.f, 0.f, 0.f};

    // prologue: stage tile 0 (S_w gll ops), prefetch x tile 0 (2 loads)
    int4 xa, xb, na, nb;
    stage(0);
    {
        const int k = kt0 * 32 + kb * 8;
        xa = *reinterpret_cast<const int4*>(xrow + k);
        xb = *reinterpret_cast<const int4*>(xrow + k + 4);
    }

    // split 15 ends its unguarded x-range at round 90 (k <= 49951 < VOCAB)
    const int nfast = (split == SPLITS - 1) ? 91 : NR;

    for (int r = 0; r < nfast; ++r) {
        // stage(r) complete (own wave: oldest S_w ops retired; x(r) may remain in flight)
        asm volatile("s_waitcnt vmcnt(2)");
        __builtin_amdgcn_sched_barrier(0);
        __builtin_amdgcn_s_barrier();         // raw barrier: NO vmcnt(0) drain
        __builtin_amdgcn_sched_barrier(0);    // keep next stage below the barrier
        if (r + 1 < nfast) {                  // issue next round: stage then x
            stage(r + 1);
            const int k = (kt0 + r + 1) * 32 + kb * 8;
            na = *reinterpret_cast<const int4*>(xrow + k);
            nb = *reinterpret_cast<const int4*>(xrow + k + 4);
        }
        // consume x(r): compiler inserts the precise vmcnt for the reg dependence
        s16x8 af = mk(xa, xb);
        const uint4* bb = bbuf[r & 1];
#pragma unroll
        for (int nt = 0; nt < NT; ++nt) {
            s16x8 bf = __builtin_bit_cast(s16x8, bb[nt * 64 + lane]);
            acc[nt] = __builtin_amdgcn_mfma_f32_16x16x32_bf16(af, bf, acc[nt], 0, 0, 0);
        }
        xa = na; xb = nb;
    }

    if (split == SPLITS - 1) {                // guarded tail, rounds 91..97
        for (int t = nfast; t < NR; ++t) {
            if (t == nfast) stage(t);
            const int k = (kt0 + t) * 32 + kb * 8;
            unsigned xv[8];
#pragma unroll
            for (int j = 0; j < 8; ++j) xv[j] = (k + j < VOCAB) ? (unsigned)xrow[k + j] : 0u;
            __syncthreads();                  // full drain: stage(t) + x visible
            uint4 apk;
            apk.x = (xv[0] + (xv[1] << 16)) * 16256u;
            apk.y = (xv[2] + (xv[3] << 16)) * 16256u;
            apk.z = (xv[4] + (xv[5] << 16)) * 16256u;
            apk.w = (xv[6] + (xv[7] << 16)) * 16256u;
            s16x8 af = __builtin_bit_cast(s16x8, apk);
            const uint4* bb = bbuf[t & 1];
#pragma unroll
            for (int nt = 0; nt < NT; ++nt) {
                s16x8 bf = __builtin_bit_cast(s16x8, bb[nt * 64 + lane]);
                acc[nt] = __builtin_amdgcn_mfma_f32_16x16x32_bf16(af, bf, acc[nt], 0, 0, 0);
            }
            if (t + 1 < NR) stage(t + 1);
        }
    }

    // D layout: row = (lane>>4)*4 + r, col = lane&15 (within the 16x16 tile)
    float* __restrict__ p = part + (size_t)split * BROWS * NCOLS;
    int m0 = mblock * 64 + wave * 16 + kb * 4;
    int c0 = lane & 15;
#pragma unroll
    for (int nt = 0; nt < NT; ++nt)
#pragma unroll
        for (int r = 0; r < 4; ++r)
            p[(size_t)(m0 + r) * NCOLS + nt * 16 + c0] = acc[nt][r];
}

// --- kernel 4: reduce splits, square-sum, add linear term ---
__global__ void fm_reduce(const float* __restrict__ part, const float* __restrict__ gbias,
                          float* __restrict__ out) {
    int b = blockIdx.x * 4 + (threadIdx.x >> 6);
    int lane = threadIdx.x & 63;
    float acc = 0.f;
#pragma unroll
    for (int s = 0; s < SPLITS; ++s)
        acc += part[((size_t)s * BROWS + b) * NCOLS + lane];
    float sq = acc * acc;
    float ex = 0.f;
    if (lane < 16)       ex = part[((size_t)lane * BROWS + b) * NCOLS + F];
    else if (lane < 32)  ex = part[((size_t)(lane - 16) * BROWS + b) * NCOLS + F + 1];
#pragma unroll
    for (int off = 32; off; off >>= 1) {
        sq += __shfl_xor(sq, off, 64);
        ex += __shfl_xor(ex, off, 64);
    }
    if (lane == 0) out[b] = gbias[0] + ex + 0.5f * sq;
}

extern "C" void kernel_launch(void* const* d_in, const int* in_sizes, int n_in,
                              void* d_out, int out_size, void* d_ws, size_t ws_size,
                              hipStream_t stream) {
    const int*   x     = (const int*)d_in[0];
    const float* V     = (const float*)d_in[1];
    const float* bias  = (const float*)d_in[2];
    const float* gbias = (const float*)d_in[3];
    float* out = (float*)d_out;

    // workspace layout
    char* ws = (char*)d_ws;
    uint4* bfrag = (uint4*)ws;                                  // 8,028,160 B
    float* w     = (float*)(ws + (size_t)KT_TOTAL * NT * 64 * 16);
    float* part  = (float*)(ws + (size_t)KT_TOTAL * NT * 64 * 16 + (size_t)KPAD * 4);
    // total: 8,028,160 + 200,704 + 20,971,520 = 29,200,384 B

    fm_prep_w<<<(KPAD + 255) / 256, 256, 0, stream>>>(V, bias, w);
    fm_prep_bfrag<<<(KT_TOTAL * NT * 64 + 255) / 256, 256, 0, stream>>>(V, w, bfrag);
    fm_main<<<(BROWS / 64) * SPLITS, 256, 0, stream>>>(x, bfrag, part);
    fm_reduce<<<BROWS / 4, 256, 0, stream>>>(part, gbias, out);
}